// Round 14
// baseline (158.011 us; speedup 1.0000x reference)
//
#include <hip/hip_runtime.h>

// SpatialTransformer: 3D trilinear warp, zeros padding.
// src [B,C,D,H,W] f32 = [2,2,128,160,128]; flow [B,3,D,H,W]; out [B,C,D,H,W].
//
// R22: HALO RADIUS 3->2 on the exact R16 structure (best: 56.4us).
// R21 post-mortem: conflicts are DATA-dependent (identical counts across
// unrelated thread maps: R16/R19 both 6858252) -> not a lever. R16's time
// = T_mem (stage 61.25KB) alternating with T_comp at 2 blocks/CU.
// R17's mistake: got 3 blocks/CU by shrinking ZT -> halo RATIO rose to
// 5.47 and it lost. Inverse move: shrink the halo RADIUS. flow ~ N(0,1);
// RZ=RY=2 misses only ~1.2% of voxels (per-dim edge fail: Phi(-2)=2.3%
// on the 2 outermost planes, avg 0.6%/dim) -> exact global fallback
// absorbs them, traffic negligible.
//  - CZ=CY=12: tile 2 x 12x12x40 x 4B = 46.08 KB -> 3 blocks/CU (138 KB)
//    AND staged/compulsory 3.83 -> 2.81 (staging 160 -> 118 MB). Both
//    T_mem and anti-phasing improve; nothing else changes.
//  - Staging: 2880 chunks, 6 x 512 with tail guard (vmcnt(0) drain via
//    __syncthreads -> per-wave count uniformity not needed).
//  - Everything else byte-identical to R16: x-quad thread map, dwordx4
//    flow/out, clamped in-bounds DMA, single barrier.
// Prediction: dur 48-52us, FETCH ~105-115MB, occupancy 42-50%.
// Pre-commit: >=55us with counters moving as predicted -> alternation
// model wrong -> XCD swizzle is the last probe, then declare at best.

#define B_ 2
#define C_ 2
#define D_ 128
#define H_ 160
#define W_ 128
constexpr int S_ = D_ * H_ * W_;

#define ZT 8
#define YT 8
#define XT 32
#define RZ 2
#define RY 2
#define RX 4
#define CZ (ZT + 2 * RZ)   // 12
#define CY (YT + 2 * RY)   // 12
#define CX (XT + 2 * RX)   // 40
#define NTHREADS 512
#define PLANE (CZ * CY * CX)        // 5760 floats per channel plane
#define CHPP (PLANE / 4)            // 1440 16B chunks per plane
#define NCHUNK_TOT (2 * CHPP)       // 2880 chunks total

typedef const __attribute__((address_space(1))) unsigned int ga_u32;
typedef __attribute__((address_space(3))) unsigned int lds_u32;

__device__ __forceinline__ void gload16(const float* g, float* l) {
    // 16B global -> LDS DMA; zero VGPR dest, vmcnt-tracked.
    __builtin_amdgcn_global_load_lds((ga_u32*)g, (lds_u32*)l, 16, 0, 0);
}

// One voxel-pair (both channels). tile = 2 planes of [CZ][CY][CX].
__device__ __forceinline__ float2 compute_pair(
    int x, int y, int z, float fz, float fy, float fx,
    int zb, int yb, int xb,
    int zlo, int zhi, int ylo, int yhi, int xlo, int xhi,
    const float* __restrict__ tile, const float* __restrict__ s0)
{
    const float iz = (float)z + fz;
    const float iy = (float)y + fy;
    const float ix = (float)x + fx;

    const float zf = floorf(iz), yf = floorf(iy), xf = floorf(ix);
    const float tz = iz - zf, ty = iy - yf, tx = ix - xf;
    const int z0 = (int)zf, y0 = (int)yf, x0 = (int)xf;

    const int zc0 = min(max(z0, 0), D_ - 1), zc1 = min(max(z0 + 1, 0), D_ - 1);
    const int yc0 = min(max(y0, 0), H_ - 1), yc1 = min(max(y0 + 1, 0), H_ - 1);
    const int xp  = min(max(x0, 0), W_ - 2);

    const float wz0 = ((unsigned)z0       < (unsigned)D_) ? (1.f - tz) : 0.f;
    const float wz1 = ((unsigned)(z0 + 1) < (unsigned)D_) ? tz         : 0.f;
    const float wy0 = ((unsigned)y0       < (unsigned)H_) ? (1.f - ty) : 0.f;
    const float wy1 = ((unsigned)(y0 + 1) < (unsigned)H_) ? ty         : 0.f;
    const float wx0 = ((unsigned)x0       < (unsigned)W_) ? (1.f - tx) : 0.f;
    const float wx1 = ((unsigned)(x0 + 1) < (unsigned)W_) ? tx         : 0.f;
    const bool hi0 = x0 > xp;   // x0 == W-1
    const bool lo1 = x0 < xp;   // x0 == -1

    const bool fast = (zc0 >= zlo) & (zc1 < zhi) &
                      (yc0 >= ylo) & (yc1 < yhi) &
                      (xp >= xlo) & (xp + 1 < xhi);

    float acc0, acc1;
    if (fast) {
        const int izl0 = zc0 - (zb - RZ), izl1 = zc1 - (zb - RZ);
        const int iyl0 = yc0 - (yb - RY), iyl1 = yc1 - (yb - RY);
        const int ixl  = xp - (xb - RX);
        const int o00 = (izl0 * CY + iyl0) * CX + ixl;
        const int o01 = (izl0 * CY + iyl1) * CX + ixl;
        const int o10 = (izl1 * CY + iyl0) * CX + ixl;
        const int o11 = (izl1 * CY + iyl1) * CX + ixl;
        const float a00 = tile[o00],         b00 = tile[o00 + 1];
        const float a01 = tile[o01],         b01 = tile[o01 + 1];
        const float a10 = tile[o10],         b10 = tile[o10 + 1];
        const float a11 = tile[o11],         b11 = tile[o11 + 1];
        const float c00 = tile[PLANE + o00], d00 = tile[PLANE + o00 + 1];
        const float c01 = tile[PLANE + o01], d01 = tile[PLANE + o01 + 1];
        const float c10 = tile[PLANE + o10], d10 = tile[PLANE + o10 + 1];
        const float c11 = tile[PLANE + o11], d11 = tile[PLANE + o11 + 1];
        const float q00 = wx0 * (hi0 ? b00 : a00) + wx1 * (lo1 ? a00 : b00);
        const float q01 = wx0 * (hi0 ? b01 : a01) + wx1 * (lo1 ? a01 : b01);
        const float q10 = wx0 * (hi0 ? b10 : a10) + wx1 * (lo1 ? a10 : b10);
        const float q11 = wx0 * (hi0 ? b11 : a11) + wx1 * (lo1 ? a11 : b11);
        const float r00 = wx0 * (hi0 ? d00 : c00) + wx1 * (lo1 ? c00 : d00);
        const float r01 = wx0 * (hi0 ? d01 : c01) + wx1 * (lo1 ? c01 : d01);
        const float r10 = wx0 * (hi0 ? d10 : c10) + wx1 * (lo1 ? c10 : d10);
        const float r11 = wx0 * (hi0 ? d11 : c11) + wx1 * (lo1 ? c11 : d11);
        acc0 = wz0 * (wy0 * q00 + wy1 * q01) + wz1 * (wy0 * q10 + wy1 * q11);
        acc1 = wz0 * (wy0 * r00 + wy1 * r01) + wz1 * (wy0 * r10 + wy1 * r11);
    } else {
        const int l00 = (zc0 * H_ + yc0) * W_ + xp;
        const int l01 = (zc0 * H_ + yc1) * W_ + xp;
        const int l10 = (zc1 * H_ + yc0) * W_ + xp;
        const int l11 = (zc1 * H_ + yc1) * W_ + xp;
        const float a00 = s0[l00],      b00 = s0[l00 + 1];
        const float a01 = s0[l01],      b01 = s0[l01 + 1];
        const float a10 = s0[l10],      b10 = s0[l10 + 1];
        const float a11 = s0[l11],      b11 = s0[l11 + 1];
        const float c00 = s0[S_ + l00], d00 = s0[S_ + l00 + 1];
        const float c01 = s0[S_ + l01], d01 = s0[S_ + l01 + 1];
        const float c10 = s0[S_ + l10], d10 = s0[S_ + l10 + 1];
        const float c11 = s0[S_ + l11], d11 = s0[S_ + l11 + 1];
        const float q00 = wx0 * (hi0 ? b00 : a00) + wx1 * (lo1 ? a00 : b00);
        const float q01 = wx0 * (hi0 ? b01 : a01) + wx1 * (lo1 ? a01 : b01);
        const float q10 = wx0 * (hi0 ? b10 : a10) + wx1 * (lo1 ? a10 : b10);
        const float q11 = wx0 * (hi0 ? b11 : a11) + wx1 * (lo1 ? a11 : b11);
        const float r00 = wx0 * (hi0 ? d00 : c00) + wx1 * (lo1 ? c00 : d00);
        const float r01 = wx0 * (hi0 ? d01 : c01) + wx1 * (lo1 ? c01 : d01);
        const float r10 = wx0 * (hi0 ? d10 : c10) + wx1 * (lo1 ? c10 : d10);
        const float r11 = wx0 * (hi0 ? d11 : c11) + wx1 * (lo1 ? c11 : d11);
        acc0 = wz0 * (wy0 * q00 + wy1 * q01) + wz1 * (wy0 * q10 + wy1 * q11);
        acc1 = wz0 * (wy0 * r00 + wy1 * r01) + wz1 * (wy0 * r10 + wy1 * r11);
    }
    return make_float2(acc0, acc1);
}

__global__ __launch_bounds__(NTHREADS, 4) void warp3d_tile(
    const float* __restrict__ src,
    const float* __restrict__ flow,
    float* __restrict__ out)
{
    __shared__ float tile[2 * PLANE];   // 11520 floats = 46.08 KB

    const int tid = threadIdx.x;
    const int xb = blockIdx.x * XT;
    const int yb = blockIdx.y * YT;
    const int bz = blockIdx.z;
    const int zb = (bz & 15) * ZT;         // 16 z-tiles
    const int b  = bz >> 4;                // batch

    const float* fb = flow + (long long)b * 3 * S_;
    const float* s0 = src + (long long)b * C_ * S_;   // ch0; ch1 = s0 + S_
    float* o0       = out + (long long)b * C_ * S_;

    // ---- staging: 2880 x 16B DMA chunks, zero VGPR dest, all clamped ----
#pragma unroll
    for (int j = 0; j < 6; ++j) {
        const int lin = j * NTHREADS + tid;
        if (lin < NCHUNK_TOT) {                // folds away for j < 5
            const int pl  = (lin >= CHPP) ? 1 : 0;
            const int rem = lin - pl * CHPP;
            const int row = rem / 10;          // rz*CY+ry, 0..143
            const int cq  = rem - row * 10;    // x-quad 0..9
            const int rz = row / CY, ry = row - rz * CY;
            const int gz = min(max(zb - RZ + rz, 0), D_ - 1);
            const int gy = min(max(yb - RY + ry, 0), H_ - 1);
            const int gx = min(max(xb - RX + cq * 4, 0), W_ - 4);
            gload16(s0 + pl * S_ + (gz * H_ + gy) * W_ + gx, &tile[lin * 4]);
        }
    }

    // ---- flow dwordx4 x3 issued while staging DMAs are in flight ----
    const int xq = tid & 7;                // 8 x-quads
    const int ly = (tid >> 3) & 7;         // 8 y
    const int lz = tid >> 6;               // 8 z
    const int x0g = xb + xq * 4;
    const int y = yb + ly, z = zb + lz;
    const int sbase = (z * H_ + y) * W_ + x0g;
    const float4 fz4 = *(const float4*)(fb + sbase);
    const float4 fy4 = *(const float4*)(fb + S_ + sbase);
    const float4 fx4 = *(const float4*)(fb + 2 * S_ + sbase);

    __syncthreads();   // single vmcnt(0) drain covers DMAs + flow

    const int zlo = max(0, zb - RZ), zhi = min(D_, zb + ZT + RZ);
    const int ylo = max(0, yb - RY), yhi = min(H_, yb + YT + RY);
    const int xlo = max(0, xb - RX), xhi = min(W_, xb + XT + RX);

    const float2 v0 = compute_pair(x0g + 0, y, z, fz4.x, fy4.x, fx4.x,
                                   zb, yb, xb, zlo, zhi, ylo, yhi, xlo, xhi, tile, s0);
    const float2 v1 = compute_pair(x0g + 1, y, z, fz4.y, fy4.y, fx4.y,
                                   zb, yb, xb, zlo, zhi, ylo, yhi, xlo, xhi, tile, s0);
    const float2 v2 = compute_pair(x0g + 2, y, z, fz4.z, fy4.z, fx4.z,
                                   zb, yb, xb, zlo, zhi, ylo, yhi, xlo, xhi, tile, s0);
    const float2 v3 = compute_pair(x0g + 3, y, z, fz4.w, fy4.w, fx4.w,
                                   zb, yb, xb, zlo, zhi, ylo, yhi, xlo, xhi, tile, s0);

    *(float4*)(o0 + sbase)      = make_float4(v0.x, v1.x, v2.x, v3.x);
    *(float4*)(o0 + S_ + sbase) = make_float4(v0.y, v1.y, v2.y, v3.y);
}

extern "C" void kernel_launch(void* const* d_in, const int* in_sizes, int n_in,
                              void* d_out, int out_size, void* d_ws, size_t ws_size,
                              hipStream_t stream) {
    const float* src  = (const float*)d_in[0];
    const float* flow = (const float*)d_in[1];
    float* out = (float*)d_out;

    // grid: x 4, y 20, z = 16 z-tiles x B2 = 32 -> 2560 blocks
    //     (~3.3 residency rounds at 3 blocks/CU).
    dim3 grid(W_ / XT, H_ / YT, (D_ / ZT) * B_);
    warp3d_tile<<<grid, NTHREADS, 0, stream>>>(src, flow, out);
}

// Round 15
// 152.331 us; speedup vs baseline: 1.0373x; 1.0373x over previous
//
#include <hip/hip_runtime.h>

// SpatialTransformer: 3D trilinear warp, zeros padding.
// src [B,C,D,H,W] f32 = [2,2,128,160,128]; flow [B,3,D,H,W]; out [B,C,D,H,W].
//
// R23: XCD-AWARE SWIZZLE on byte-identical R16 (best: 56.4us). Last
// pre-committed probe. R22 post-mortem: halo 3->2 lost (61.6us) because
// fallback rate x4 -> ~95% of waves eat a serial post-barrier global
// gather chain; radius 3 is the operating point.
// R16's residual over-fetch (120 vs 105 MB compulsory) = halo re-staging
// resolved in L3 because default dispatch round-robins consecutive block
// IDs across XCDs (neighbors share 43% of halo rows but live on different
// L2s). Bijective T1 swizzle (nwg=2560, 2560%8==0): XCD k gets contiguous
// [k*320,(k+1)*320) = 4 whole z-slices. One z-slice's staged set (14
// z-planes x 160y x 128x x 2ch x 4B = 2.3 MB) fits the 4 MB XCD L2 ->
// y-halo (co-resident) and z-halo (next round) re-stage become L2 hits.
//  - 1D grid 2560; in-kernel decode: swz = (flat%8)*320 + flat/8;
//    xi = swz&3, yi = (swz>>2)%20, zi = swz/80 (zb=(zi&15)*8, b=zi>>4).
//  - Everything else identical to R16 (geometry, DMA staging, barrier,
//    thread map, fallback).
// Prediction: FETCH 120 -> 106-112 MB; dur 52-55us; all else unchanged.
// Pre-commit: dur >= 55us -> structural wall established at R16-class;
// declare next round.

#define B_ 2
#define C_ 2
#define D_ 128
#define H_ 160
#define W_ 128
constexpr int S_ = D_ * H_ * W_;

#define ZT 8
#define YT 8
#define XT 32
#define RZ 3
#define RY 3
#define RX 4
#define CZ (ZT + 2 * RZ)   // 14
#define CY (YT + 2 * RY)   // 14
#define CX (XT + 2 * RX)   // 40
#define NTHREADS 512
#define PLANE (CZ * CY * CX)        // 7840 floats per channel plane
#define CHPP (PLANE / 4)            // 1960 16B chunks per plane
#define NCHUNK_TOT (2 * CHPP)       // 3920 chunks total
#define NWG 2560
#define NXCD 8
#define CPX (NWG / NXCD)            // 320 blocks per XCD chunk

typedef const __attribute__((address_space(1))) unsigned int ga_u32;
typedef __attribute__((address_space(3))) unsigned int lds_u32;

__device__ __forceinline__ void gload16(const float* g, float* l) {
    // 16B global -> LDS DMA; zero VGPR dest, vmcnt-tracked.
    __builtin_amdgcn_global_load_lds((ga_u32*)g, (lds_u32*)l, 16, 0, 0);
}

// One voxel-pair (both channels). tile = 2 planes of [CZ][CY][CX].
__device__ __forceinline__ float2 compute_pair(
    int x, int y, int z, float fz, float fy, float fx,
    int zb, int yb, int xb,
    int zlo, int zhi, int ylo, int yhi, int xlo, int xhi,
    const float* __restrict__ tile, const float* __restrict__ s0)
{
    const float iz = (float)z + fz;
    const float iy = (float)y + fy;
    const float ix = (float)x + fx;

    const float zf = floorf(iz), yf = floorf(iy), xf = floorf(ix);
    const float tz = iz - zf, ty = iy - yf, tx = ix - xf;
    const int z0 = (int)zf, y0 = (int)yf, x0 = (int)xf;

    const int zc0 = min(max(z0, 0), D_ - 1), zc1 = min(max(z0 + 1, 0), D_ - 1);
    const int yc0 = min(max(y0, 0), H_ - 1), yc1 = min(max(y0 + 1, 0), H_ - 1);
    const int xp  = min(max(x0, 0), W_ - 2);

    const float wz0 = ((unsigned)z0       < (unsigned)D_) ? (1.f - tz) : 0.f;
    const float wz1 = ((unsigned)(z0 + 1) < (unsigned)D_) ? tz         : 0.f;
    const float wy0 = ((unsigned)y0       < (unsigned)H_) ? (1.f - ty) : 0.f;
    const float wy1 = ((unsigned)(y0 + 1) < (unsigned)H_) ? ty         : 0.f;
    const float wx0 = ((unsigned)x0       < (unsigned)W_) ? (1.f - tx) : 0.f;
    const float wx1 = ((unsigned)(x0 + 1) < (unsigned)W_) ? tx         : 0.f;
    const bool hi0 = x0 > xp;   // x0 == W-1
    const bool lo1 = x0 < xp;   // x0 == -1

    const bool fast = (zc0 >= zlo) & (zc1 < zhi) &
                      (yc0 >= ylo) & (yc1 < yhi) &
                      (xp >= xlo) & (xp + 1 < xhi);

    float acc0, acc1;
    if (fast) {
        const int izl0 = zc0 - (zb - RZ), izl1 = zc1 - (zb - RZ);
        const int iyl0 = yc0 - (yb - RY), iyl1 = yc1 - (yb - RY);
        const int ixl  = xp - (xb - RX);
        const int o00 = (izl0 * CY + iyl0) * CX + ixl;
        const int o01 = (izl0 * CY + iyl1) * CX + ixl;
        const int o10 = (izl1 * CY + iyl0) * CX + ixl;
        const int o11 = (izl1 * CY + iyl1) * CX + ixl;
        const float a00 = tile[o00],         b00 = tile[o00 + 1];
        const float a01 = tile[o01],         b01 = tile[o01 + 1];
        const float a10 = tile[o10],         b10 = tile[o10 + 1];
        const float a11 = tile[o11],         b11 = tile[o11 + 1];
        const float c00 = tile[PLANE + o00], d00 = tile[PLANE + o00 + 1];
        const float c01 = tile[PLANE + o01], d01 = tile[PLANE + o01 + 1];
        const float c10 = tile[PLANE + o10], d10 = tile[PLANE + o10 + 1];
        const float c11 = tile[PLANE + o11], d11 = tile[PLANE + o11 + 1];
        const float q00 = wx0 * (hi0 ? b00 : a00) + wx1 * (lo1 ? a00 : b00);
        const float q01 = wx0 * (hi0 ? b01 : a01) + wx1 * (lo1 ? a01 : b01);
        const float q10 = wx0 * (hi0 ? b10 : a10) + wx1 * (lo1 ? a10 : b10);
        const float q11 = wx0 * (hi0 ? b11 : a11) + wx1 * (lo1 ? a11 : b11);
        const float r00 = wx0 * (hi0 ? d00 : c00) + wx1 * (lo1 ? c00 : d00);
        const float r01 = wx0 * (hi0 ? d01 : c01) + wx1 * (lo1 ? c01 : d01);
        const float r10 = wx0 * (hi0 ? d10 : c10) + wx1 * (lo1 ? c10 : d10);
        const float r11 = wx0 * (hi0 ? d11 : c11) + wx1 * (lo1 ? c11 : d11);
        acc0 = wz0 * (wy0 * q00 + wy1 * q01) + wz1 * (wy0 * q10 + wy1 * q11);
        acc1 = wz0 * (wy0 * r00 + wy1 * r01) + wz1 * (wy0 * r10 + wy1 * r11);
    } else {
        const int l00 = (zc0 * H_ + yc0) * W_ + xp;
        const int l01 = (zc0 * H_ + yc1) * W_ + xp;
        const int l10 = (zc1 * H_ + yc0) * W_ + xp;
        const int l11 = (zc1 * H_ + yc1) * W_ + xp;
        const float a00 = s0[l00],      b00 = s0[l00 + 1];
        const float a01 = s0[l01],      b01 = s0[l01 + 1];
        const float a10 = s0[l10],      b10 = s0[l10 + 1];
        const float a11 = s0[l11],      b11 = s0[l11 + 1];
        const float c00 = s0[S_ + l00], d00 = s0[S_ + l00 + 1];
        const float c01 = s0[S_ + l01], d01 = s0[S_ + l01 + 1];
        const float c10 = s0[S_ + l10], d10 = s0[S_ + l10 + 1];
        const float c11 = s0[S_ + l11], d11 = s0[S_ + l11 + 1];
        const float q00 = wx0 * (hi0 ? b00 : a00) + wx1 * (lo1 ? a00 : b00);
        const float q01 = wx0 * (hi0 ? b01 : a01) + wx1 * (lo1 ? a01 : b01);
        const float q10 = wx0 * (hi0 ? b10 : a10) + wx1 * (lo1 ? a10 : b10);
        const float q11 = wx0 * (hi0 ? b11 : a11) + wx1 * (lo1 ? a11 : b11);
        const float r00 = wx0 * (hi0 ? d00 : c00) + wx1 * (lo1 ? c00 : d00);
        const float r01 = wx0 * (hi0 ? d01 : c01) + wx1 * (lo1 ? c01 : d01);
        const float r10 = wx0 * (hi0 ? d10 : c10) + wx1 * (lo1 ? c10 : d10);
        const float r11 = wx0 * (hi0 ? d11 : c11) + wx1 * (lo1 ? c11 : d11);
        acc0 = wz0 * (wy0 * q00 + wy1 * q01) + wz1 * (wy0 * q10 + wy1 * q11);
        acc1 = wz0 * (wy0 * r00 + wy1 * r01) + wz1 * (wy0 * r10 + wy1 * r11);
    }
    return make_float2(acc0, acc1);
}

__global__ __launch_bounds__(NTHREADS, 4) void warp3d_tile(
    const float* __restrict__ src,
    const float* __restrict__ flow,
    float* __restrict__ out)
{
    __shared__ float tile[2 * PLANE];   // 15680 floats = 61.25 KB

    const int tid = threadIdx.x;

    // ---- XCD-aware bijective swizzle: XCD k owns [k*320, (k+1)*320) ----
    const int flat = blockIdx.x;                  // 0..2559
    const int swz  = (flat & (NXCD - 1)) * CPX + (flat >> 3);
    const int xi = swz & 3;                       // 4 x-tiles
    const int rest = swz >> 2;
    const int yi = rest % 20;                     // 20 y-tiles
    const int zi = rest / 20;                     // 32 (16 z-tiles x 2 batch)
    const int xb = xi * XT;
    const int yb = yi * YT;
    const int zb = (zi & 15) * ZT;
    const int b  = zi >> 4;

    const float* fb = flow + (long long)b * 3 * S_;
    const float* s0 = src + (long long)b * C_ * S_;   // ch0; ch1 = s0 + S_
    float* o0       = out + (long long)b * C_ * S_;

    // ---- staging: 3920 x 16B DMA chunks, zero VGPR dest, all clamped ----
#pragma unroll
    for (int j = 0; j < 8; ++j) {
        const int lin = j * NTHREADS + tid;
        if (lin < NCHUNK_TOT) {                // folds away for j < 7
            const int pl  = (lin >= CHPP) ? 1 : 0;
            const int rem = lin - pl * CHPP;
            const int row = rem / 10;          // rz*CY+ry, 0..195
            const int cq  = rem - row * 10;    // x-quad 0..9
            const int rz = row / CY, ry = row - rz * CY;
            const int gz = min(max(zb - RZ + rz, 0), D_ - 1);
            const int gy = min(max(yb - RY + ry, 0), H_ - 1);
            const int gx = min(max(xb - RX + cq * 4, 0), W_ - 4);
            gload16(s0 + pl * S_ + (gz * H_ + gy) * W_ + gx, &tile[lin * 4]);
        }
    }

    // ---- flow dwordx4 x3 issued while staging DMAs are in flight ----
    const int xq = tid & 7;                // 8 x-quads
    const int ly = (tid >> 3) & 7;         // 8 y
    const int lz = tid >> 6;               // 8 z
    const int x0g = xb + xq * 4;
    const int y = yb + ly, z = zb + lz;
    const int sbase = (z * H_ + y) * W_ + x0g;
    const float4 fz4 = *(const float4*)(fb + sbase);
    const float4 fy4 = *(const float4*)(fb + S_ + sbase);
    const float4 fx4 = *(const float4*)(fb + 2 * S_ + sbase);

    __syncthreads();   // single vmcnt(0) drain covers DMAs + flow

    const int zlo = max(0, zb - RZ), zhi = min(D_, zb + ZT + RZ);
    const int ylo = max(0, yb - RY), yhi = min(H_, yb + YT + RY);
    const int xlo = max(0, xb - RX), xhi = min(W_, xb + XT + RX);

    const float2 v0 = compute_pair(x0g + 0, y, z, fz4.x, fy4.x, fx4.x,
                                   zb, yb, xb, zlo, zhi, ylo, yhi, xlo, xhi, tile, s0);
    const float2 v1 = compute_pair(x0g + 1, y, z, fz4.y, fy4.y, fx4.y,
                                   zb, yb, xb, zlo, zhi, ylo, yhi, xlo, xhi, tile, s0);
    const float2 v2 = compute_pair(x0g + 2, y, z, fz4.z, fy4.z, fx4.z,
                                   zb, yb, xb, zlo, zhi, ylo, yhi, xlo, xhi, tile, s0);
    const float2 v3 = compute_pair(x0g + 3, y, z, fz4.w, fy4.w, fx4.w,
                                   zb, yb, xb, zlo, zhi, ylo, yhi, xlo, xhi, tile, s0);

    *(float4*)(o0 + sbase)      = make_float4(v0.x, v1.x, v2.x, v3.x);
    *(float4*)(o0 + S_ + sbase) = make_float4(v0.y, v1.y, v2.y, v3.y);
}

extern "C" void kernel_launch(void* const* d_in, const int* in_sizes, int n_in,
                              void* d_out, int out_size, void* d_ws, size_t ws_size,
                              hipStream_t stream) {
    const float* src  = (const float*)d_in[0];
    const float* flow = (const float*)d_in[1];
    float* out = (float*)d_out;

    // 1D grid 2560 (= 4x x 20y x 32zb); swizzle decoded in-kernel.
    warp3d_tile<<<dim3(NWG, 1, 1), NTHREADS, 0, stream>>>(src, flow, out);
}